// Round 13
// baseline (773.535 us; speedup 1.0000x reference)
//
#include <hip/hip_runtime.h>
#include <hip/hip_cooperative_groups.h>
#include <math.h>

namespace cg = cooperative_groups;

#define BZ   8
#define DDIM 128
#define NN   2048
#define KSEL 30
#define KEEP 1024
#define ROWS 8

// ---------- block reductions (blockDim == 256) ----------
__device__ __forceinline__ double blockReduceD(double x, double* lds) {
  #pragma unroll
  for (int off = 32; off; off >>= 1) x += __shfl_down(x, off, 64);
  int wv = threadIdx.x >> 6;
  __syncthreads();
  if ((threadIdx.x & 63) == 0) lds[wv] = x;
  __syncthreads();
  return lds[0] + lds[1] + lds[2] + lds[3];
}

// ================= fast path: single cooperative mega-kernel ==============
// Grid sized at launch from the occupancy query (expect 8 blocks/CU at
// VGPR=64 -> grid 2048). ALL phases are grid-stride loops, so any grid
// size >= 64 is correct. Phase bodies verbatim from the round-9 kernels
// (bitwise-identical math).
__global__ __launch_bounds__(256, 2) void k_mega(
    const float* __restrict__ data, float* __restrict__ xnT,
    double* __restrict__ panelD, double* __restrict__ sq,
    float* __restrict__ distM, float* __restrict__ kth,
    float* __restrict__ Rf, float* __restrict__ samples,
    float* __restrict__ neigh, float* __restrict__ degree,
    float* __restrict__ score, float* __restrict__ mask,
    float* __restrict__ outp) {
  cg::grid_group gg = cg::this_grid();
  const int blk = blockIdx.x;
  const int GD = gridDim.x;
  const int t = threadIdx.x;
  __shared__ double ldsD[4];
  __shared__ float msd[2];
  __shared__ float mfs;
  __shared__ float sc[NN];             // 8 KB (rank phase)
  __shared__ int pS[4];

  // ---- phase 1: per-(b,feature) normalize + fp64 panel (1024 jobs) ----
  for (int job = blk; job < 1024; job += GD) {
    const float* src = data + (size_t)job * NN;
    float* dst = xnT + (size_t)job * NN;
    float v[8];
    double s = 0.0, s2 = 0.0;
    #pragma unroll
    for (int q = 0; q < 8; ++q) {
      v[q] = src[t + q * 256];
      double d = (double)v[q];
      s += d;
      s2 = fma(d, d, s2);
    }
    s  = blockReduceD(s, ldsD);
    s2 = blockReduceD(s2, ldsD);
    if (t == 0) {
      double mean = s * (1.0 / 2048.0);
      double var = (s2 - s * mean) / 2047.0;
      if (var < 0.0) var = 0.0;
      msd[0] = (float)mean;
      msd[1] = (float)sqrt(var);
    }
    __syncthreads();
    const float mean = msd[0];
    const float den = msd[1] + 1e-6f;
    const int b = job >> 7, d = job & 127;
    #pragma unroll
    for (int q = 0; q < 8; ++q) {
      const int n = t + q * 256;
      const float xn = (v[q] - mean) / den;   // fp32 rounding point
      dst[n] = xn;
      panelD[(size_t)(b * 256 + (n >> 3)) * 1024 + d * 8 + (n & 7)] = (double)xn;
    }
    __syncthreads();
  }
  gg.sync();

  // ---- phase 2: sq[b][n] = sum_d Xn^2 (fp64 chain) ----
  for (int gid = blk * 256 + t; gid < BZ * NN; gid += GD * 256) {
    const int b = gid >> 11, n = gid & 2047;
    const float* X = xnT + (size_t)b * DDIM * NN + n;
    double s = 0.0;
    for (int d = 0; d < DDIM; ++d) {
      double x = (double)X[(size_t)d * NN];
      s = fma(x, x, s);
    }
    sq[gid] = s;
  }
  gg.sync();

  // ---- phase 3: cyclic-halved symmetric fp64 GEMM (2048 jobs) ----
  for (int job = blk; job < 2048; job += GD) {
    const int b = job & 7;
    const int g = job >> 3;              // 0..255
    const int i0 = g << 3;
    const int c = (i0 + (t << 2)) & (NN - 1);
    const float*  cp = xnT + (size_t)b * DDIM * NN + c;
    const double* rp = panelD + ((size_t)(b * 256 + g) << 10);   // [d][8]

    double acc[ROWS][4];
    #pragma unroll
    for (int r = 0; r < ROWS; ++r)
      #pragma unroll
      for (int q = 0; q < 4; ++q) acc[r][q] = 0.0;

    #pragma unroll 2
    for (int d = 0; d < DDIM; ++d) {
      const float4 c0 = *(const float4*)(cp + ((size_t)d << 11));
      const double cd0 = (double)c0.x, cd1 = (double)c0.y;
      const double cd2 = (double)c0.z, cd3 = (double)c0.w;
      #pragma unroll
      for (int r = 0; r < ROWS; ++r) {
        const double rv = rp[(d << 3) + r];   // block-uniform -> s_load
        acc[r][0] = fma(rv, cd0, acc[r][0]);
        acc[r][1] = fma(rv, cd1, acc[r][1]);
        acc[r][2] = fma(rv, cd2, acc[r][2]);
        acc[r][3] = fma(rv, cd3, acc[r][3]);
      }
    }

    const double* sqb = sq + (b << 11);
    const double sqc0 = sqb[c], sqc1 = sqb[c + 1], sqc2 = sqb[c + 2], sqc3 = sqb[c + 3];
    float f[ROWS][4];
    #pragma unroll
    for (int r = 0; r < ROWS; ++r) {
      const double sqi = sqb[i0 + r];
      double d2;
      d2 = (sqi + sqc0) - 2.0 * acc[r][0]; if (d2 < 0.0) d2 = 0.0; f[r][0] = (float)sqrt(d2);
      d2 = (sqi + sqc1) - 2.0 * acc[r][1]; if (d2 < 0.0) d2 = 0.0; f[r][1] = (float)sqrt(d2);
      d2 = (sqi + sqc2) - 2.0 * acc[r][2]; if (d2 < 0.0) d2 = 0.0; f[r][2] = (float)sqrt(d2);
      d2 = (sqi + sqc3) - 2.0 * acc[r][3]; if (d2 < 0.0) d2 = 0.0; f[r][3] = (float)sqrt(d2);
      *(float4*)(distM + (((size_t)((b << 11) + i0 + r)) << 11) + c) =
          make_float4(f[r][0], f[r][1], f[r][2], f[r][3]);
    }
    #pragma unroll
    for (int q = 0; q < 4; ++q) {
      float* trow = distM + (((size_t)((b << 11) + c + q)) << 11) + i0;
      *(float4*)(trow)     = make_float4(f[0][q], f[1][q], f[2][q], f[3][q]);
      *(float4*)(trow + 4) = make_float4(f[4][q], f[5][q], f[6][q], f[7][q]);
    }
  }
  // antipodal tiles (separation 128): 256 block-quanta of 4 8x8 tiles
  for (int bq = blk; bq < 256; bq += GD) {
    const int a = bq * 4 + (t >> 6);     // 0..1023
    const int b = a & 7;
    const int g = a >> 3;                // 0..127
    const int i0 = g << 3;
    const int j0 = i0 + 1024;
    const int l = t & 63;
    const int r = l >> 3, q = l & 7;
    const double* rp = panelD + ((size_t)(b * 256 + g) << 10);
    const float*  cp = xnT + (size_t)b * DDIM * NN + j0 + q;
    double acc = 0.0;
    for (int d = 0; d < DDIM; ++d)
      acc = fma(rp[(d << 3) + r], (double)cp[(size_t)d << 11], acc);
    const double* sqb = sq + (b << 11);
    double d2 = (sqb[i0 + r] + sqb[j0 + q]) - 2.0 * acc;
    if (d2 < 0.0) d2 = 0.0;
    const float f = (float)sqrt(d2);
    distM[(((size_t)((b << 11) + i0 + r)) << 11) + j0 + q] = f;
    distM[(((size_t)((b << 11) + j0 + q)) << 11) + i0 + r] = f;
  }
  gg.sync();

  // ---- phase 4: wave-per-row radix select ----
  {
    const int w = t >> 6, l = t & 63;
    for (int row = blk * 4 + w; row < BZ * NN; row += GD * 4) {
      const float4* r4 = (const float4*)(distM + ((size_t)row << 11));
      unsigned u[32];
      #pragma unroll
      for (int jj = 0; jj < 8; ++jj) {
        const float4 fv = r4[(jj << 6) + l];
        u[jj * 4 + 0] = __float_as_uint(fv.x);
        u[jj * 4 + 1] = __float_as_uint(fv.y);
        u[jj * 4 + 2] = __float_as_uint(fv.z);
        u[jj * 4 + 3] = __float_as_uint(fv.w);
      }
      unsigned pref = 0;
      for (int bit = 30; bit >= 0; --bit) {
        const unsigned mid = pref | (1u << bit);
        int c = 0;
        #pragma unroll
        for (int k = 0; k < 32; ++k)
          c += (int)__popcll(__ballot(u[k] < mid));
        if (c <= KSEL) pref = mid;
      }
      if (l == 0) kth[row] = __uint_as_float(pref);
    }
  }
  gg.sync();

  // ---- phase 5: Rf[b] = mean(kth row) (8 jobs) ----
  for (int bb = blk; bb < 8; bb += GD) {
    const float* p = kth + (bb << 11);
    double s = 0.0;
    #pragma unroll
    for (int q = 0; q < 8; ++q) s += (double)p[t + q * 256];
    s = blockReduceD(s, ldsD);
    if (t == 0) Rf[bb] = (float)(s * (1.0 / 2048.0));
  }
  gg.sync();

  // ---- phase 6: counts; samples by row scan, neighbors by king gather ----
  {
    const int w = t >> 6, l = t & 63;
    for (int job = blk; job < BZ * NN; job += GD) {
      const int b = job >> 11, i = job & 2047;
      const float R = Rf[b];
      const float* drow = distM + ((size_t)job << 11);
      const float4* d4 = (const float4*)drow + (t << 1);
      const float4 d0 = d4[0], d1 = d4[1];
      const float f[8] = {d0.x, d0.y, d0.z, d0.w, d1.x, d1.y, d1.z, d1.w};
      int sN = 0;
      #pragma unroll
      for (int q = 0; q < 8; ++q) sN += (int)__popcll(__ballot(f[q] < R));
      if (l == 0) pS[w] = sN;
      __syncthreads();
      if (t < 64) {
        bool inb = false, ok = false;
        if (l < 8) {
          const int m = (l < 4) ? l : l + 1;          // skip (0,0)
          const int di = m / 3 - 1, dj = m % 3 - 1;   // king-move offsets
          const int rj = (i >> 6) + di, cj = (i & 63) + dj;
          inb = ((unsigned)rj < 32u) && ((unsigned)cj < 64u);
          if (inb) {
            const float fv = drow[(rj << 6) + cj];
            ok = (fv != 0.0f) && (fv < R);
          }
        }
        const int nN = (int)__popcll(__ballot(ok));
        const int dc = (int)__popcll(__ballot(inb));
        if (t == 0) {
          samples[job] = (float)(pS[0] + pS[1] + pS[2] + pS[3]);
          neigh[job]   = (float)nN;
          if (b == 0) degree[i] = (float)dc;
        }
      }
      __syncthreads();   // protect pS before next job
    }
  }
  gg.sync();

  // ---- phase 7: mean(samples) + score + stable rank + mask (64 jobs) ----
  for (int bb = blk; bb < 64; bb += GD) {
    const int b = bb >> 3, chunk = bb & 7;
    const float* p = samples + (b << 11);
    double s = 0.0;
    #pragma unroll
    for (int q = 0; q < 8; ++q) s += (double)p[t + q * 256];
    s = blockReduceD(s, ldsD);
    if (t == 0) mfs = (float)(s * (1.0 / 2048.0));
    __syncthreads();
    const float mf = mfs;
    #pragma unroll
    for (int q = 0; q < 8; ++q) {
      const int i = t + q * 256;
      const int g = (b << 11) + i;
      const float sp = neigh[g] / degree[i];
      const float sv = p[i];
      const float tp = sv / (sv + mf);
      const float v = (2.0f - sp) - tp;
      sc[i] = v;
      if (chunk == 0) score[g] = v;
    }
    __syncthreads();
    const int i = chunk * 256 + t;
    const float si = sc[i];
    int less = 0, eqb = 0;
    for (int j = 0; j < NN; ++j) {
      const float sj = sc[j];
      less += (sj < si) ? 1 : 0;
      eqb  += ((sj == si) && (j < i)) ? 1 : 0;
    }
    mask[(b << 11) + i] = ((less + eqb) < KEEP) ? 1.0f : 0.0f;
    __syncthreads();
  }
  gg.sync();

  // ---- phase 8: out = data * mask ----
  for (int g = blk * 256 + t; g < 524288; g += GD * 256) {
    const float4 dv = ((const float4*)data)[g];
    const int idx = g << 2;
    const int b = idx >> 18;
    const int w2 = idx & 2047;
    const float4 mk = *(const float4*)(mask + (b << 11) + w2);
    float4 o;
    o.x = dv.x * mk.x; o.y = dv.y * mk.y; o.z = dv.z * mk.z; o.w = dv.w * mk.w;
    ((float4*)outp)[g] = o;
  }
}

// ================= fallback: proven round-9 multi-kernel path =============
__global__ __launch_bounds__(256) void k_norm(const float* __restrict__ data,
                                              float* __restrict__ xnT,
                                              double* __restrict__ panelD) {
  __shared__ double lds[4];
  __shared__ float msd[2];
  const int blk = blockIdx.x;
  const int t = threadIdx.x;
  const float* src = data + (size_t)blk * NN;
  float v[8];
  double s = 0.0, s2 = 0.0;
  #pragma unroll
  for (int q = 0; q < 8; ++q) {
    v[q] = src[t + q * 256];
    double d = (double)v[q];
    s += d;
    s2 = fma(d, d, s2);
  }
  s  = blockReduceD(s, lds);
  s2 = blockReduceD(s2, lds);
  if (t == 0) {
    double mean = s * (1.0 / 2048.0);
    double var = (s2 - s * mean) / 2047.0;
    if (var < 0.0) var = 0.0;
    msd[0] = (float)mean;
    msd[1] = (float)sqrt(var);
  }
  __syncthreads();
  const float mean = msd[0];
  const float den = msd[1] + 1e-6f;
  const int b = blk >> 7, d = blk & 127;
  #pragma unroll
  for (int q = 0; q < 8; ++q) {
    const int n = t + q * 256;
    const float xn = (v[q] - mean) / den;
    xnT[(size_t)blk * NN + n] = xn;
    panelD[(size_t)(b * 256 + (n >> 3)) * 1024 + d * 8 + (n & 7)] = (double)xn;
  }
}

__global__ __launch_bounds__(256) void k_sq(const float* __restrict__ xnT,
                                            double* __restrict__ sq) {
  const int g = blockIdx.x * 256 + threadIdx.x;
  const int b = g >> 11, n = g & 2047;
  const float* X = xnT + (size_t)b * DDIM * NN + n;
  double s = 0.0;
  for (int d = 0; d < DDIM; ++d) {
    double x = (double)X[(size_t)d * NN];
    s = fma(x, x, s);
  }
  sq[g] = s;
}

__global__ __launch_bounds__(256, 4) void k_gemm_sgpr(
    const float* __restrict__ xnT, const double* __restrict__ panelD,
    const double* __restrict__ sq, float* __restrict__ distM) {
  const int t = threadIdx.x;
  if (blockIdx.x < 2048) {
    const int b = blockIdx.x & 7;
    const int g = blockIdx.x >> 3;
    const int i0 = g << 3;
    const int c = (i0 + (t << 2)) & (NN - 1);
    const float*  cp = xnT + (size_t)b * DDIM * NN + c;
    const double* rp = panelD + ((size_t)(b * 256 + g) << 10);
    double acc[ROWS][4];
    #pragma unroll
    for (int r = 0; r < ROWS; ++r)
      #pragma unroll
      for (int q = 0; q < 4; ++q) acc[r][q] = 0.0;
    #pragma unroll 2
    for (int d = 0; d < DDIM; ++d) {
      const float4 c0 = *(const float4*)(cp + ((size_t)d << 11));
      const double cd0 = (double)c0.x, cd1 = (double)c0.y;
      const double cd2 = (double)c0.z, cd3 = (double)c0.w;
      #pragma unroll
      for (int r = 0; r < ROWS; ++r) {
        const double rv = rp[(d << 3) + r];
        acc[r][0] = fma(rv, cd0, acc[r][0]);
        acc[r][1] = fma(rv, cd1, acc[r][1]);
        acc[r][2] = fma(rv, cd2, acc[r][2]);
        acc[r][3] = fma(rv, cd3, acc[r][3]);
      }
    }
    const double* sqb = sq + (b << 11);
    const double sqc0 = sqb[c], sqc1 = sqb[c + 1], sqc2 = sqb[c + 2], sqc3 = sqb[c + 3];
    float f[ROWS][4];
    #pragma unroll
    for (int r = 0; r < ROWS; ++r) {
      const double sqi = sqb[i0 + r];
      double d2;
      d2 = (sqi + sqc0) - 2.0 * acc[r][0]; if (d2 < 0.0) d2 = 0.0; f[r][0] = (float)sqrt(d2);
      d2 = (sqi + sqc1) - 2.0 * acc[r][1]; if (d2 < 0.0) d2 = 0.0; f[r][1] = (float)sqrt(d2);
      d2 = (sqi + sqc2) - 2.0 * acc[r][2]; if (d2 < 0.0) d2 = 0.0; f[r][2] = (float)sqrt(d2);
      d2 = (sqi + sqc3) - 2.0 * acc[r][3]; if (d2 < 0.0) d2 = 0.0; f[r][3] = (float)sqrt(d2);
      *(float4*)(distM + (((size_t)((b << 11) + i0 + r)) << 11) + c) =
          make_float4(f[r][0], f[r][1], f[r][2], f[r][3]);
    }
    #pragma unroll
    for (int q = 0; q < 4; ++q) {
      float* trow = distM + (((size_t)((b << 11) + c + q)) << 11) + i0;
      *(float4*)(trow)     = make_float4(f[0][q], f[1][q], f[2][q], f[3][q]);
      *(float4*)(trow + 4) = make_float4(f[4][q], f[5][q], f[6][q], f[7][q]);
    }
  } else {
    const int a = (blockIdx.x - 2048) * 4 + (t >> 6);
    const int b = a & 7;
    const int g = a >> 3;
    const int i0 = g << 3;
    const int j0 = i0 + 1024;
    const int l = t & 63;
    const int r = l >> 3, q = l & 7;
    const double* rp = panelD + ((size_t)(b * 256 + g) << 10);
    const float*  cp = xnT + (size_t)b * DDIM * NN + j0 + q;
    double acc = 0.0;
    for (int d = 0; d < DDIM; ++d)
      acc = fma(rp[(d << 3) + r], (double)cp[(size_t)d << 11], acc);
    const double* sqb = sq + (b << 11);
    double d2 = (sqb[i0 + r] + sqb[j0 + q]) - 2.0 * acc;
    if (d2 < 0.0) d2 = 0.0;
    const float f = (float)sqrt(d2);
    distM[(((size_t)((b << 11) + i0 + r)) << 11) + j0 + q] = f;
    distM[(((size_t)((b << 11) + j0 + q)) << 11) + i0 + r] = f;
  }
}

__global__ __launch_bounds__(256) void k_sel(const float* __restrict__ dist,
                                             float* __restrict__ kth) {
  const int row = (blockIdx.x << 2) + (threadIdx.x >> 6);
  const int l = threadIdx.x & 63;
  const float4* r4 = (const float4*)(dist + ((size_t)row << 11));
  unsigned u[32];
  #pragma unroll
  for (int jj = 0; jj < 8; ++jj) {
    const float4 fv = r4[(jj << 6) + l];
    u[jj * 4 + 0] = __float_as_uint(fv.x);
    u[jj * 4 + 1] = __float_as_uint(fv.y);
    u[jj * 4 + 2] = __float_as_uint(fv.z);
    u[jj * 4 + 3] = __float_as_uint(fv.w);
  }
  unsigned pref = 0;
  for (int bit = 30; bit >= 0; --bit) {
    const unsigned mid = pref | (1u << bit);
    int c = 0;
    #pragma unroll
    for (int k = 0; k < 32; ++k)
      c += (int)__popcll(__ballot(u[k] < mid));
    if (c <= KSEL) pref = mid;
  }
  if (l == 0) kth[row] = __uint_as_float(pref);
}

__global__ __launch_bounds__(256) void k_mean2048(const float* __restrict__ in,
                                                  float* __restrict__ out) {
  __shared__ double lds[4];
  const int b = blockIdx.x, t = threadIdx.x;
  const float* p = in + (b << 11);
  double s = 0.0;
  #pragma unroll
  for (int q = 0; q < 8; ++q) s += (double)p[t + q * 256];
  s = blockReduceD(s, lds);
  if (t == 0) out[b] = (float)(s * (1.0 / 2048.0));
}

__global__ __launch_bounds__(256) void k_count_geo(
    const float* __restrict__ dist, const float* __restrict__ Rf,
    float* __restrict__ samples, float* __restrict__ neigh,
    float* __restrict__ degree) {
  __shared__ int pS[4];
  const int bi = blockIdx.x;
  const int b = bi >> 11, i = bi & 2047;
  const int t = threadIdx.x, w = t >> 6, l = t & 63;
  const float R = Rf[b];
  const float* drow = dist + ((size_t)bi << 11);
  const float4* d4 = (const float4*)drow + (t << 1);
  const float4 d0 = d4[0], d1 = d4[1];
  const float f[8] = {d0.x, d0.y, d0.z, d0.w, d1.x, d1.y, d1.z, d1.w};
  int sN = 0;
  #pragma unroll
  for (int q = 0; q < 8; ++q) sN += (int)__popcll(__ballot(f[q] < R));
  if (l == 0) pS[w] = sN;
  __syncthreads();
  if (t < 64) {
    bool inb = false, ok = false;
    if (l < 8) {
      const int m = (l < 4) ? l : l + 1;
      const int di = m / 3 - 1, dj = m % 3 - 1;
      const int rj = (i >> 6) + di, cj = (i & 63) + dj;
      inb = ((unsigned)rj < 32u) && ((unsigned)cj < 64u);
      if (inb) {
        const float fv = drow[(rj << 6) + cj];
        ok = (fv != 0.0f) && (fv < R);
      }
    }
    const int nN = (int)__popcll(__ballot(ok));
    const int dc = (int)__popcll(__ballot(inb));
    if (t == 0) {
      samples[bi] = (float)(pS[0] + pS[1] + pS[2] + pS[3]);
      neigh[bi]   = (float)nN;
      if (b == 0) degree[i] = (float)dc;
    }
  }
}

__global__ __launch_bounds__(256) void k_rank_score(
    const float* __restrict__ samples, const float* __restrict__ neigh,
    const float* __restrict__ degree, float* __restrict__ score,
    float* __restrict__ mask) {
  __shared__ double lds[4];
  __shared__ float mfs;
  __shared__ float sc[NN];
  const int b = blockIdx.x >> 3, chunk = blockIdx.x & 7, t = threadIdx.x;
  const float* p = samples + (b << 11);
  double s = 0.0;
  #pragma unroll
  for (int q = 0; q < 8; ++q) s += (double)p[t + q * 256];
  s = blockReduceD(s, lds);
  if (t == 0) mfs = (float)(s * (1.0 / 2048.0));
  __syncthreads();
  const float mf = mfs;
  #pragma unroll
  for (int q = 0; q < 8; ++q) {
    const int i = t + q * 256;
    const int g = (b << 11) + i;
    const float sp = neigh[g] / degree[i];
    const float sv = p[i];
    const float tp = sv / (sv + mf);
    const float v = (2.0f - sp) - tp;
    sc[i] = v;
    if (chunk == 0) score[g] = v;
  }
  __syncthreads();
  const int i = chunk * 256 + t;
  const float si = sc[i];
  int less = 0, eqb = 0;
  for (int j = 0; j < NN; ++j) {
    const float sj = sc[j];
    less += (sj < si) ? 1 : 0;
    eqb  += ((sj == si) && (j < i)) ? 1 : 0;
  }
  mask[(b << 11) + i] = ((less + eqb) < KEEP) ? 1.0f : 0.0f;
}

__global__ __launch_bounds__(256) void k_apply(const float* __restrict__ data,
                                               const float* __restrict__ mask,
                                               float* __restrict__ out) {
  const int g = blockIdx.x * 256 + threadIdx.x;
  const float4 d = ((const float4*)data)[g];
  const int idx = g << 2;
  const int b = idx >> 18;
  const int w = idx & 2047;
  const float4 mk = *(const float4*)(mask + (b << 11) + w);
  float4 o;
  o.x = d.x * mk.x; o.y = d.y * mk.y; o.z = d.z * mk.z; o.w = d.w * mk.w;
  ((float4*)out)[g] = o;
}

extern "C" void kernel_launch(void* const* d_in, const int* in_sizes, int n_in,
                              void* d_out, int out_size, void* d_ws, size_t ws_size,
                              hipStream_t stream) {
  (void)in_sizes; (void)n_in; (void)out_size; (void)ws_size;
  const float* data = (const float*)d_in[0];
  float* out = (float*)d_out;

  float* xnT   = out;             // fp32 Xn staged in output, overwritten last
  float* score = out + 2097152;   // total_score output slot (8*2048)

  uint8_t* w = (uint8_t*)d_ws;
  double* sq      = (double*)(w);            // 131072 B
  float*  kth     = (float*)(w + 131072);    // 65536 B
  float*  Rf      = (float*)(w + 196608);    // 32 B
  float*  samples = (float*)(w + 196672);    // 65536 B
  float*  neigh   = (float*)(w + 262208);    // 65536 B
  float*  degree  = (float*)(w + 327808);    // 8192 B
  float*  mask    = (float*)(w + 336000);    // 65536 B

  const size_t panelBytes = (size_t)BZ * DDIM * NN * sizeof(double); // 16777216
  double* panelD = (double*)(w + 1048576);
  float*  distM  = (float*)(w + 1048576 + panelBytes);

  void* kargs[13];
  kargs[0]  = (void*)&data;
  kargs[1]  = (void*)&xnT;
  kargs[2]  = (void*)&panelD;
  kargs[3]  = (void*)&sq;
  kargs[4]  = (void*)&distM;
  kargs[5]  = (void*)&kth;
  kargs[6]  = (void*)&Rf;
  kargs[7]  = (void*)&samples;
  kargs[8]  = (void*)&neigh;
  kargs[9]  = (void*)&degree;
  kargs[10] = (void*)&score;
  kargs[11] = (void*)&mask;
  kargs[12] = (void*)&out;

  // Size the cooperative grid from the real occupancy (host queries only —
  // deterministic, graph-capture-safe).
  int dev = 0;
  (void)hipGetDevice(&dev);
  int numCU = 0;
  (void)hipDeviceGetAttribute(&numCU, hipDeviceAttributeMultiprocessorCount, dev);
  int maxB = 0;
  (void)hipOccupancyMaxActiveBlocksPerMultiprocessor(
      &maxB, reinterpret_cast<const void*>(k_mega), 256, 0);
  long long grid = (long long)numCU * (long long)maxB;
  if (grid > 2048) grid = 2048;

  hipError_t err = hipErrorUnknown;
  if (grid >= 64) {
    err = hipLaunchCooperativeKernel(reinterpret_cast<void*>(k_mega),
                                     dim3((unsigned)grid), dim3(256),
                                     kargs, 0, stream);
  }

  if (err != hipSuccess) {
    (void)hipGetLastError();   // clear sticky error, use proven multi-kernel path
    k_norm<<<1024, 256, 0, stream>>>(data, xnT, panelD);
    k_sq  <<<64,   256, 0, stream>>>(xnT, sq);
    k_gemm_sgpr<<<2304, 256, 0, stream>>>(xnT, panelD, sq, distM);
    k_sel <<<4096, 256, 0, stream>>>(distM, kth);
    k_mean2048<<<8, 256, 0, stream>>>(kth, Rf);
    k_count_geo<<<16384, 256, 0, stream>>>(distM, Rf, samples, neigh, degree);
    k_rank_score<<<64, 256, 0, stream>>>(samples, neigh, degree, score, mask);
    k_apply<<<2048, 256, 0, stream>>>(data, mask, out);
  }
}

// Round 14
// 420.891 us; speedup vs baseline: 1.8379x; 1.8379x over previous
//
#include <hip/hip_runtime.h>
#include <math.h>

#define BZ   8
#define DDIM 128
#define NN   2048
#define KSEL 30
#define KEEP 1024
#define ROWS 8

typedef double f64x4 __attribute__((ext_vector_type(4)));

// ---------- block reduction (blockDim == 256) ----------
__device__ __forceinline__ double blockReduceD(double x, double* lds) {
  #pragma unroll
  for (int off = 32; off; off >>= 1) x += __shfl_down(x, off, 64);
  int wv = threadIdx.x >> 6;
  __syncthreads();
  if ((threadIdx.x & 63) == 0) lds[wv] = x;
  __syncthreads();
  return lds[0] + lds[1] + lds[2] + lds[3];
}

// ---------- K1: normalize -> fp64 xnD [b][d][n]; zero the check flag ------
__global__ __launch_bounds__(256) void k_normD(const float* __restrict__ data,
                                               double* __restrict__ xnD,
                                               int* __restrict__ flag) {
  __shared__ double lds[4];
  __shared__ float msd[2];
  const int blk = blockIdx.x;          // b*128 + d
  const int t = threadIdx.x;
  if (blk == 0 && t == 0) *flag = 0;   // deterministic init each call
  const float* src = data + (size_t)blk * NN;
  float v[8];
  double s = 0.0, s2 = 0.0;
  #pragma unroll
  for (int q = 0; q < 8; ++q) {
    v[q] = src[t + q * 256];
    double d = (double)v[q];
    s += d;
    s2 = fma(d, d, s2);
  }
  s  = blockReduceD(s, lds);
  s2 = blockReduceD(s2, lds);
  if (t == 0) {
    double mean = s * (1.0 / 2048.0);
    double var = (s2 - s * mean) / 2047.0;
    if (var < 0.0) var = 0.0;
    msd[0] = (float)mean;
    msd[1] = (float)sqrt(var);
  }
  __syncthreads();
  const float mean = msd[0];
  const float den = msd[1] + 1e-6f;
  #pragma unroll
  for (int q = 0; q < 8; ++q) {
    const float xn = (v[q] - mean) / den;       // fp32 rounding point
    xnD[(size_t)blk * NN + t + q * 256] = (double)xn;   // exact widen
  }
}

// ---------- K2: sq[b][n] = sum_d Xn^2 (fp64 chain) ----------
__global__ __launch_bounds__(256) void k_sqD(const double* __restrict__ xnD,
                                             double* __restrict__ sq) {
  const int g = blockIdx.x * 256 + threadIdx.x;
  const int b = g >> 11, n = g & 2047;
  const double* X = xnD + (size_t)b * DDIM * NN + n;
  double s = 0.0;
  for (int d = 0; d < DDIM; ++d) {
    const double x = X[(size_t)d << 11];
    s = fma(x, x, s);
  }
  sq[g] = s;
}

// ---------- K3: fp64 MFMA distance GEMM, 16x16 tiles, cyclic half ---------
// grid 1024: blk = g*8 + b. Row-tile g (16 rows I=16g); col window of 64
// 16-col tiles (g+m)&127, m=0..63 (separations 0..63; sep 64 -> k_anti16).
// Wave w owns m = w,w+4,..; per tile: 32x mfma_f64_16x16x4 over d.
// Assumed fragments: A[i][k]: lane=(k<<4)|i ; B[k][j]: lane=(k<<4)|j ;
// D[i][j]: j=lane&15, i=(lane>>4)*4+reg. Verified on-device by k_check;
// wrong mapping -> flag -> k_cyc_cond recomputes everything (VALU path).
__global__ __launch_bounds__(256) void k_mfma(const double* __restrict__ xnD,
                                              const double* __restrict__ sq,
                                              float* __restrict__ distM) {
  const int t = threadIdx.x;
  const int b = blockIdx.x & 7;
  const int g = blockIdx.x >> 3;        // 0..127
  const int I = g << 4;
  const int w = t >> 6, l = t & 63;
  const int lr = l & 15;                // row (A) / col (B,D)
  const int lk = l >> 4;                // k-slot 0..3
  const double* Xb = xnD + (size_t)b * DDIM * NN;
  const double* sqb = sq + (b << 11);

  // preload the 32 A fragments (rows I..I+15, all 128 d in 4-slices)
  double Afrag[32];
  #pragma unroll
  for (int ks = 0; ks < 32; ++ks)
    Afrag[ks] = Xb[((size_t)((ks << 2) + lk) << 11) + I + lr];

  // row-side sq for the epilogue (D rows = I + lk*4 + j)
  double sqr[4];
  #pragma unroll
  for (int j = 0; j < 4; ++j) sqr[j] = sqb[I + (lk << 2) + j];

  for (int m = w; m < 64; m += 4) {
    const int J = ((g + m) & 127) << 4;
    f64x4 acc = {0.0, 0.0, 0.0, 0.0};
    #pragma unroll
    for (int ks = 0; ks < 32; ++ks) {
      const double Bfrag = Xb[((size_t)((ks << 2) + lk) << 11) + J + lr];
      acc = __builtin_amdgcn_mfma_f64_16x16x4f64(Afrag[ks], Bfrag, acc, 0, 0, 0);
    }
    const int col = J + lr;
    const double sqc = sqb[col];
    float fv[4];
    #pragma unroll
    for (int j = 0; j < 4; ++j) {
      double d2 = (sqr[j] + sqc) - 2.0 * acc[j];
      if (d2 < 0.0) d2 = 0.0;
      fv[j] = (float)sqrt(d2);
      const int row = I + (lk << 2) + j;
      distM[(((size_t)((b << 11) + row)) << 11) + col] = fv[j];
    }
    #pragma unroll
    for (int j = 0; j < 4; ++j) {
      const int row = I + (lk << 2) + j;
      distM[(((size_t)((b << 11) + col)) << 11) + row] = fv[j];
    }
  }
}

// ---------- K3a: antipodal 16x16 tiles (16-tile separation 64) ------------
// grid 512: blk = G*8 + b, G in [0,64). Rows [16G,+16) x cols [16G+1024,+16).
// Plain fp64 d-ascending chain (independent of MFMA correctness).
__global__ __launch_bounds__(256) void k_anti16(const double* __restrict__ xnD,
                                                const double* __restrict__ sq,
                                                float* __restrict__ distM) {
  __shared__ double rowd[DDIM][16];   // 16 KB
  __shared__ double cold[DDIM][16];   // 16 KB
  const int b = blockIdx.x & 7;
  const int G = blockIdx.x >> 3;      // 0..63
  const int i0 = G << 4;
  const int j0 = i0 + 1024;
  const int t = threadIdx.x;
  const double* Xb = xnD + (size_t)b * DDIM * NN;
  #pragma unroll
  for (int q = 0; q < 8; ++q) {
    const int idx = (t << 3) + q;     // 0..2047
    const int d = idx >> 4, r = idx & 15;
    rowd[d][r] = Xb[((size_t)d << 11) + i0 + r];
    cold[d][r] = Xb[((size_t)d << 11) + j0 + r];
  }
  __syncthreads();
  const int r = t >> 4, q = t & 15;
  double acc = 0.0;
  for (int d = 0; d < DDIM; ++d)
    acc = fma(rowd[d][r], cold[d][q], acc);
  const double* sqb = sq + (b << 11);
  double d2 = (sqb[i0 + r] + sqb[j0 + q]) - 2.0 * acc;
  if (d2 < 0.0) d2 = 0.0;
  const float f = (float)sqrt(d2);
  distM[(((size_t)((b << 11) + i0 + r)) << 11) + j0 + q] = f;
  distM[(((size_t)((b << 11) + j0 + q)) << 11) + i0 + r] = f;
}

// ---------- K3b: verify one MFMA tile (+mirror) per batch ----------
// grid 8 x 256: tile g=5 (I=80), m=7 -> J=192. Direct fp64 dot reference.
// Wrong fragment mapping shifts values by O(0.1-1) >> 1e-3 tol; legitimate
// accumulation-order deltas are ~1e-6 after fp32 rounding.
__global__ __launch_bounds__(256) void k_check(const double* __restrict__ xnD,
                                               const double* __restrict__ sq,
                                               const float* __restrict__ distM,
                                               int* __restrict__ flag) {
  const int b = blockIdx.x;
  const int t = threadIdx.x;
  const int i = 80 + (t >> 4);
  const int j = 192 + (t & 15);
  const double* Xb = xnD + (size_t)b * DDIM * NN;
  double dot = 0.0;
  for (int d = 0; d < DDIM; ++d)
    dot = fma(Xb[((size_t)d << 11) + i], Xb[((size_t)d << 11) + j], dot);
  const double* sqb = sq + (b << 11);
  double d2 = (sqb[i] + sqb[j]) - 2.0 * dot;
  if (d2 < 0.0) d2 = 0.0;
  const float fc = (float)sqrt(d2);
  const float fm = distM[(((size_t)((b << 11) + i)) << 11) + j];
  const float fm2 = distM[(((size_t)((b << 11) + j)) << 11) + i];
  if (fabsf(fc - fm) > 1e-3f || fabsf(fc - fm2) > 1e-3f)
    atomicOr(flag, 1);
}

// ---------- K3c: conditional VALU fallback (round-6 cyclic GEMM) ----------
// Runs only if k_check flagged; overwrites all 16-sep 0..63 entries (the
// MFMA coverage). Proven structure from round 6 (131 us, passed).
__global__ __launch_bounds__(256, 3) void k_cyc_cond(
    const double* __restrict__ xnD, const double* __restrict__ sq,
    float* __restrict__ distM, const int* __restrict__ flag) {
  if (*flag == 0) return;             // uniform early-exit
  __shared__ double rowd[DDIM][ROWS]; // 8 KB
  const int b = blockIdx.x & 7;
  const int g = blockIdx.x >> 3;      // 0..255
  const int i0 = g << 3;
  const int t = threadIdx.x;
  const double* Xb = xnD + (size_t)b * DDIM * NN;
  #pragma unroll
  for (int q = 0; q < 4; ++q) {
    const int idx = (t << 2) + q;
    const int d = idx >> 3, r = idx & 7;
    rowd[d][r] = Xb[((size_t)d << 11) + i0 + r];
  }
  __syncthreads();
  const int c = (i0 + (t << 2)) & (NN - 1);
  double acc[ROWS][4];
  #pragma unroll
  for (int r = 0; r < ROWS; ++r)
    #pragma unroll
    for (int q = 0; q < 4; ++q) acc[r][q] = 0.0;
  const double* colp = Xb + c;
  for (int d = 0; d < DDIM; ++d) {
    const double* cp = colp + ((size_t)d << 11);
    const double2 p0 = *(const double2*)cp;
    const double2 p1 = *(const double2*)(cp + 2);
    #pragma unroll
    for (int r = 0; r < ROWS; ++r) {
      const double rv = rowd[d][r];
      acc[r][0] = fma(rv, p0.x, acc[r][0]);
      acc[r][1] = fma(rv, p0.y, acc[r][1]);
      acc[r][2] = fma(rv, p1.x, acc[r][2]);
      acc[r][3] = fma(rv, p1.y, acc[r][3]);
    }
  }
  const double* sqb = sq + (b << 11);
  const double sqc0 = sqb[c], sqc1 = sqb[c + 1], sqc2 = sqb[c + 2], sqc3 = sqb[c + 3];
  float f[ROWS][4];
  #pragma unroll
  for (int r = 0; r < ROWS; ++r) {
    const double sqi = sqb[i0 + r];
    double d2;
    d2 = (sqi + sqc0) - 2.0 * acc[r][0]; if (d2 < 0.0) d2 = 0.0; f[r][0] = (float)sqrt(d2);
    d2 = (sqi + sqc1) - 2.0 * acc[r][1]; if (d2 < 0.0) d2 = 0.0; f[r][1] = (float)sqrt(d2);
    d2 = (sqi + sqc2) - 2.0 * acc[r][2]; if (d2 < 0.0) d2 = 0.0; f[r][2] = (float)sqrt(d2);
    d2 = (sqi + sqc3) - 2.0 * acc[r][3]; if (d2 < 0.0) d2 = 0.0; f[r][3] = (float)sqrt(d2);
    *(float4*)(distM + (((size_t)((b << 11) + i0 + r)) << 11) + c) =
        make_float4(f[r][0], f[r][1], f[r][2], f[r][3]);
  }
  #pragma unroll
  for (int q = 0; q < 4; ++q) {
    float* trow = distM + (((size_t)((b << 11) + c + q)) << 11) + i0;
    *(float4*)(trow)     = make_float4(f[0][q], f[1][q], f[2][q], f[3][q]);
    *(float4*)(trow + 4) = make_float4(f[4][q], f[5][q], f[6][q], f[7][q]);
  }
}

// ---------- K4: wave-per-row radix select (count(u<mid) form) ----------
__global__ __launch_bounds__(256) void k_sel(const float* __restrict__ dist,
                                             float* __restrict__ kth) {
  const int row = (blockIdx.x << 2) + (threadIdx.x >> 6);
  const int l = threadIdx.x & 63;
  const float4* r4 = (const float4*)(dist + ((size_t)row << 11));
  unsigned u[32];
  #pragma unroll
  for (int jj = 0; jj < 8; ++jj) {
    const float4 fv = r4[(jj << 6) + l];
    u[jj * 4 + 0] = __float_as_uint(fv.x);
    u[jj * 4 + 1] = __float_as_uint(fv.y);
    u[jj * 4 + 2] = __float_as_uint(fv.z);
    u[jj * 4 + 3] = __float_as_uint(fv.w);
  }
  unsigned pref = 0;
  for (int bit = 30; bit >= 0; --bit) {
    const unsigned mid = pref | (1u << bit);
    int c = 0;
    #pragma unroll
    for (int k = 0; k < 32; ++k)
      c += (int)__popcll(__ballot(u[k] < mid));
    if (c <= KSEL) pref = mid;
  }
  if (l == 0) kth[row] = __uint_as_float(pref);
}

// ---------- K5: mean of 2048 floats ----------
__global__ __launch_bounds__(256) void k_mean2048(const float* __restrict__ in,
                                                  float* __restrict__ out) {
  __shared__ double lds[4];
  const int b = blockIdx.x, t = threadIdx.x;
  const float* p = in + (b << 11);
  double s = 0.0;
  #pragma unroll
  for (int q = 0; q < 8; ++q) s += (double)p[t + q * 256];
  s = blockReduceD(s, lds);
  if (t == 0) out[b] = (float)(s * (1.0 / 2048.0));
}

// ---------- K6: counts; samples by row scan, neighbors by king gather ----
__global__ __launch_bounds__(256) void k_count_geo(
    const float* __restrict__ dist, const float* __restrict__ Rf,
    float* __restrict__ samples, float* __restrict__ neigh,
    float* __restrict__ degree) {
  __shared__ int pS[4];
  const int bi = blockIdx.x;
  const int b = bi >> 11, i = bi & 2047;
  const int t = threadIdx.x, w = t >> 6, l = t & 63;
  const float R = Rf[b];
  const float* drow = dist + ((size_t)bi << 11);
  const float4* d4 = (const float4*)drow + (t << 1);
  const float4 d0 = d4[0], d1 = d4[1];
  const float f[8] = {d0.x, d0.y, d0.z, d0.w, d1.x, d1.y, d1.z, d1.w};
  int sN = 0;
  #pragma unroll
  for (int q = 0; q < 8; ++q) sN += (int)__popcll(__ballot(f[q] < R));
  if (l == 0) pS[w] = sN;
  __syncthreads();
  if (t < 64) {
    bool inb = false, ok = false;
    if (l < 8) {
      const int m = (l < 4) ? l : l + 1;
      const int di = m / 3 - 1, dj = m % 3 - 1;
      const int rj = (i >> 6) + di, cj = (i & 63) + dj;
      inb = ((unsigned)rj < 32u) && ((unsigned)cj < 64u);
      if (inb) {
        const float fv = drow[(rj << 6) + cj];
        ok = (fv != 0.0f) && (fv < R);
      }
    }
    const int nN = (int)__popcll(__ballot(ok));
    const int dc = (int)__popcll(__ballot(inb));
    if (t == 0) {
      samples[bi] = (float)(pS[0] + pS[1] + pS[2] + pS[3]);
      neigh[bi]   = (float)nN;
      if (b == 0) degree[i] = (float)dc;
    }
  }
}

// ---------- K7: mean(samples) + score + stable rank + mask ----------
__global__ __launch_bounds__(256) void k_rank_score(
    const float* __restrict__ samples, const float* __restrict__ neigh,
    const float* __restrict__ degree, float* __restrict__ score,
    float* __restrict__ mask) {
  __shared__ double lds[4];
  __shared__ float mfs;
  __shared__ float sc[NN];
  const int b = blockIdx.x >> 3, chunk = blockIdx.x & 7, t = threadIdx.x;
  const float* p = samples + (b << 11);
  double s = 0.0;
  #pragma unroll
  for (int q = 0; q < 8; ++q) s += (double)p[t + q * 256];
  s = blockReduceD(s, lds);
  if (t == 0) mfs = (float)(s * (1.0 / 2048.0));
  __syncthreads();
  const float mf = mfs;
  #pragma unroll
  for (int q = 0; q < 8; ++q) {
    const int i = t + q * 256;
    const int g = (b << 11) + i;
    const float sp = neigh[g] / degree[i];
    const float sv = p[i];
    const float tp = sv / (sv + mf);
    const float v = (2.0f - sp) - tp;
    sc[i] = v;
    if (chunk == 0) score[g] = v;
  }
  __syncthreads();
  const int i = chunk * 256 + t;
  const float si = sc[i];
  int less = 0, eqb = 0;
  for (int j = 0; j < NN; ++j) {
    const float sj = sc[j];
    less += (sj < si) ? 1 : 0;
    eqb  += ((sj == si) && (j < i)) ? 1 : 0;
  }
  mask[(b << 11) + i] = ((less + eqb) < KEEP) ? 1.0f : 0.0f;
}

// ---------- K8: out = data * mask ----------
__global__ __launch_bounds__(256) void k_apply(const float* __restrict__ data,
                                               const float* __restrict__ mask,
                                               float* __restrict__ out) {
  const int g = blockIdx.x * 256 + threadIdx.x;
  const float4 d = ((const float4*)data)[g];
  const int idx = g << 2;
  const int b = idx >> 18;
  const int w = idx & 2047;
  const float4 mk = *(const float4*)(mask + (b << 11) + w);
  float4 o;
  o.x = d.x * mk.x; o.y = d.y * mk.y; o.z = d.z * mk.z; o.w = d.w * mk.w;
  ((float4*)out)[g] = o;
}

extern "C" void kernel_launch(void* const* d_in, const int* in_sizes, int n_in,
                              void* d_out, int out_size, void* d_ws, size_t ws_size,
                              hipStream_t stream) {
  (void)in_sizes; (void)n_in; (void)out_size; (void)ws_size;
  const float* data = (const float*)d_in[0];
  float* out = (float*)d_out;
  float* score = out + 2097152;   // total_score output slot (8*2048)

  uint8_t* w = (uint8_t*)d_ws;
  double* sq      = (double*)(w);            // 131072 B
  float*  kth     = (float*)(w + 131072);    // 65536 B
  float*  Rf      = (float*)(w + 196608);    // 32 B
  float*  samples = (float*)(w + 196672);    // 65536 B
  float*  neigh   = (float*)(w + 262208);    // 65536 B
  int*    flag    = (int*)  (w + 327744);    // 4 B
  float*  degree  = (float*)(w + 327808);    // 8192 B
  float*  mask    = (float*)(w + 336000);    // 65536 B

  const size_t xnDBytes = (size_t)BZ * DDIM * NN * sizeof(double); // 16777216
  double* xnD   = (double*)(w + 1048576);
  float*  distM = (float*)(w + 1048576 + xnDBytes);

  k_normD<<<1024, 256, 0, stream>>>(data, xnD, flag);
  k_sqD  <<<64,   256, 0, stream>>>(xnD, sq);
  k_mfma <<<1024, 256, 0, stream>>>(xnD, sq, distM);
  k_anti16<<<512, 256, 0, stream>>>(xnD, sq, distM);
  k_check<<<8,    256, 0, stream>>>(xnD, sq, distM, flag);
  k_cyc_cond<<<2048, 256, 0, stream>>>(xnD, sq, distM, flag);
  k_sel  <<<4096, 256, 0, stream>>>(distM, kth);
  k_mean2048<<<8, 256, 0, stream>>>(kth, Rf);
  k_count_geo<<<16384, 256, 0, stream>>>(distM, Rf, samples, neigh, degree);
  k_rank_score<<<64, 256, 0, stream>>>(samples, neigh, degree, score, mask);
  k_apply<<<2048, 256, 0, stream>>>(data, mask, out);
}

// Round 15
// 368.756 us; speedup vs baseline: 2.0977x; 1.1414x over previous
//
#include <hip/hip_runtime.h>
#include <math.h>

#define BZ   8
#define DDIM 128
#define NN   2048
#define KSEL 30
#define KEEP 1024
#define ROWS 8

typedef double f64x4 __attribute__((ext_vector_type(4)));

// ---------- block reduction (blockDim == 256) ----------
__device__ __forceinline__ double blockReduceD(double x, double* lds) {
  #pragma unroll
  for (int off = 32; off; off >>= 1) x += __shfl_down(x, off, 64);
  int wv = threadIdx.x >> 6;
  __syncthreads();
  if ((threadIdx.x & 63) == 0) lds[wv] = x;
  __syncthreads();
  return lds[0] + lds[1] + lds[2] + lds[3];
}

// ---------- K1: normalize -> fp64 xnD [b][d][n]; zero the flag ------------
__global__ __launch_bounds__(256) void k_normD(const float* __restrict__ data,
                                               double* __restrict__ xnD,
                                               int* __restrict__ flag) {
  __shared__ double lds[4];
  __shared__ float msd[2];
  const int blk = blockIdx.x;          // b*128 + d
  const int t = threadIdx.x;
  if (blk == 0 && t == 0) *flag = 0;   // deterministic init each call
  const float* src = data + (size_t)blk * NN;
  float v[8];
  double s = 0.0, s2 = 0.0;
  #pragma unroll
  for (int q = 0; q < 8; ++q) {
    v[q] = src[t + q * 256];
    double d = (double)v[q];
    s += d;
    s2 = fma(d, d, s2);
  }
  s  = blockReduceD(s, lds);
  s2 = blockReduceD(s2, lds);
  if (t == 0) {
    double mean = s * (1.0 / 2048.0);
    double var = (s2 - s * mean) / 2047.0;
    if (var < 0.0) var = 0.0;
    msd[0] = (float)mean;
    msd[1] = (float)sqrt(var);
  }
  __syncthreads();
  const float mean = msd[0];
  const float den = msd[1] + 1e-6f;
  #pragma unroll
  for (int q = 0; q < 8; ++q) {
    const float xn = (v[q] - mean) / den;       // fp32 rounding point
    xnD[(size_t)blk * NN + t + q * 256] = (double)xn;   // exact widen
  }
}

// ---------- K2: sq (blocks 0..63) + MFMA layout probe (block 64) ----------
// Probe: compute gram tile (rows 80..95 x cols 192..207, b=0) directly and
// via MFMA with the main kernel's load scheme; match values to recover the
// true (lane,reg)->(row,col) map. Any ambiguity/mismatch -> flag=1.
__global__ __launch_bounds__(256) void k_sq_probe(const double* __restrict__ xnD,
                                                  double* __restrict__ sq,
                                                  int* __restrict__ flag,
                                                  int* __restrict__ rowmap,
                                                  int* __restrict__ colmap) {
  const int t = threadIdx.x;
  if (blockIdx.x < 64) {
    const int g = blockIdx.x * 256 + t;
    const int b = g >> 11, n = g & 2047;
    const double* X = xnD + (size_t)b * DDIM * NN + n;
    double s = 0.0;
    for (int d = 0; d < DDIM; ++d) {
      const double x = X[(size_t)d << 11];
      s = fma(x, x, s);
    }
    sq[g] = s;
    return;
  }
  // ---- probe block ----
  __shared__ double rowL[DDIM][16];   // 16 KB  rows 80..95
  __shared__ double colL[DDIM][16];   // 16 KB  cols 192..207
  __shared__ double ref[16][16];      // 2 KB
  __shared__ double Dm[64][4];        // 2 KB
  __shared__ int hits[256];
  const double* X0 = xnD;             // batch 0
  #pragma unroll
  for (int q = 0; q < 8; ++q) {
    const int idx = (t << 3) + q;     // 0..2047
    const int d = idx >> 4, r = idx & 15;
    rowL[d][r] = X0[((size_t)d << 11) + 80 + r];
    colL[d][r] = X0[((size_t)d << 11) + 192 + r];
  }
  hits[t] = 0;
  __syncthreads();
  {
    const int i = t >> 4, j = t & 15;
    double dot = 0.0;
    for (int d = 0; d < DDIM; ++d)
      dot = fma(rowL[d][i], colL[d][j], dot);
    ref[i][j] = dot;
  }
  if (t < 64) {
    const int lr = t & 15, lk = t >> 4;
    f64x4 acc = {0.0, 0.0, 0.0, 0.0};
    #pragma unroll
    for (int ks = 0; ks < 32; ++ks) {
      const int d = (ks << 2) + lk;
      acc = __builtin_amdgcn_mfma_f64_16x16x4f64(rowL[d][lr], colL[d][lr],
                                                 acc, 0, 0, 0);
    }
    #pragma unroll
    for (int r = 0; r < 4; ++r) Dm[t][r] = acc[r];
  }
  __syncthreads();
  // match slot t = lane*4+reg against the 256 reference values
  {
    const double val = Dm[t >> 2][t & 3];
    int cnt = 0, mi = -1, mj = -1;
    for (int ii = 0; ii < 16; ++ii)
      #pragma unroll 4
      for (int jj = 0; jj < 16; ++jj)
        if (fabs(val - ref[ii][jj]) < 1e-9) { ++cnt; mi = ii; mj = jj; }
    if (cnt != 1) atomicOr(flag, 1);
    else {
      rowmap[t] = mi;
      colmap[t] = mj;
      atomicAdd(&hits[mi * 16 + mj], 1);
    }
  }
  __syncthreads();
  if (hits[t] != 1) atomicOr(flag, 1);   // must be a bijection
}

// ---------- K3: fp64 MFMA distance GEMM, adaptive layout, 2-tile pipe -----
// grid 1024: blk = g*8 + b. Rows I=16g; 64 col-tiles (g+m)&127, m=0..63.
// Wave w handles pairs (w+8p, w+4+8p), p=0..7 -> two independent acc chains.
// Epilogue places results via probed rowmap/colmap. Early-exit on flag.
__global__ __launch_bounds__(256) void k_mfma(const double* __restrict__ xnD,
                                              const double* __restrict__ sq,
                                              float* __restrict__ distM,
                                              const int* __restrict__ flag,
                                              const int* __restrict__ rowmap,
                                              const int* __restrict__ colmap) {
  if (*flag) return;                    // probe failed -> VALU fallback path
  const int t = threadIdx.x;
  const int b = blockIdx.x & 7;
  const int g = blockIdx.x >> 3;        // 0..127
  const int I = g << 4;
  const int w = t >> 6, l = t & 63;
  const int lr = l & 15;
  const int lk = l >> 4;
  const double* Xb = xnD + (size_t)b * DDIM * NN;
  const double* sqb = sq + (b << 11);

  int rm[4], cm[4];
  #pragma unroll
  for (int r = 0; r < 4; ++r) {
    rm[r] = rowmap[(l << 2) + r];
    cm[r] = colmap[(l << 2) + r];
  }

  double Afrag[32];
  #pragma unroll
  for (int ks = 0; ks < 32; ++ks)
    Afrag[ks] = Xb[((size_t)((ks << 2) + lk) << 11) + I + lr];

  for (int p = 0; p < 8; ++p) {
    const int ma = w + (p << 3);
    const int mb = ma + 4;
    const int Ja = ((g + ma) & 127) << 4;
    const int Jb = ((g + mb) & 127) << 4;
    const double* pa = Xb + Ja + lr;
    const double* pb = Xb + Jb + lr;
    f64x4 accA = {0.0, 0.0, 0.0, 0.0};
    f64x4 accB = {0.0, 0.0, 0.0, 0.0};
    #pragma unroll
    for (int ks = 0; ks < 32; ++ks) {
      const size_t off = (size_t)((ks << 2) + lk) << 11;
      const double Ba = pa[off];
      const double Bb = pb[off];
      accA = __builtin_amdgcn_mfma_f64_16x16x4f64(Afrag[ks], Ba, accA, 0, 0, 0);
      accB = __builtin_amdgcn_mfma_f64_16x16x4f64(Afrag[ks], Bb, accB, 0, 0, 0);
    }
    #pragma unroll
    for (int r = 0; r < 4; ++r) {
      const int row = I + rm[r];
      const int col = Ja + cm[r];
      double d2 = (sqb[row] + sqb[col]) - 2.0 * accA[r];
      if (d2 < 0.0) d2 = 0.0;
      const float fv = (float)sqrt(d2);
      distM[(((size_t)((b << 11) + row)) << 11) + col] = fv;
      distM[(((size_t)((b << 11) + col)) << 11) + row] = fv;
    }
    #pragma unroll
    for (int r = 0; r < 4; ++r) {
      const int row = I + rm[r];
      const int col = Jb + cm[r];
      double d2 = (sqb[row] + sqb[col]) - 2.0 * accB[r];
      if (d2 < 0.0) d2 = 0.0;
      const float fv = (float)sqrt(d2);
      distM[(((size_t)((b << 11) + row)) << 11) + col] = fv;
      distM[(((size_t)((b << 11) + col)) << 11) + row] = fv;
    }
  }
}

// ---------- K3a: antipodal 16x16 tiles (blocks<512) + check (blocks>=512) -
__global__ __launch_bounds__(256) void k_anti_check(
    const double* __restrict__ xnD, const double* __restrict__ sq,
    float* __restrict__ distM, int* __restrict__ flag) {
  const int t = threadIdx.x;
  if (blockIdx.x < 512) {
    __shared__ double rowd[DDIM][16];
    __shared__ double cold[DDIM][16];
    const int b = blockIdx.x & 7;
    const int G = blockIdx.x >> 3;      // 0..63
    const int i0 = G << 4;
    const int j0 = i0 + 1024;
    const double* Xb = xnD + (size_t)b * DDIM * NN;
    #pragma unroll
    for (int q = 0; q < 8; ++q) {
      const int idx = (t << 3) + q;
      const int d = idx >> 4, r = idx & 15;
      rowd[d][r] = Xb[((size_t)d << 11) + i0 + r];
      cold[d][r] = Xb[((size_t)d << 11) + j0 + r];
    }
    __syncthreads();
    const int r = t >> 4, q = t & 15;
    double acc = 0.0;
    for (int d = 0; d < DDIM; ++d)
      acc = fma(rowd[d][r], cold[d][q], acc);
    const double* sqb = sq + (b << 11);
    double d2 = (sqb[i0 + r] + sqb[j0 + q]) - 2.0 * acc;
    if (d2 < 0.0) d2 = 0.0;
    const float f = (float)sqrt(d2);
    distM[(((size_t)((b << 11) + i0 + r)) << 11) + j0 + q] = f;
    distM[(((size_t)((b << 11) + j0 + q)) << 11) + i0 + r] = f;
  } else {
    // verify one MFMA tile (+mirror) per batch against direct fp64 dots
    const int b = blockIdx.x - 512;     // 0..7
    const int i = 80 + (t >> 4);
    const int j = 192 + (t & 15);
    const double* Xb = xnD + (size_t)b * DDIM * NN;
    double dot = 0.0;
    for (int d = 0; d < DDIM; ++d)
      dot = fma(Xb[((size_t)d << 11) + i], Xb[((size_t)d << 11) + j], dot);
    const double* sqb = sq + (b << 11);
    double d2 = (sqb[i] + sqb[j]) - 2.0 * dot;
    if (d2 < 0.0) d2 = 0.0;
    const float fc = (float)sqrt(d2);
    const float fm = distM[(((size_t)((b << 11) + i)) << 11) + j];
    const float fm2 = distM[(((size_t)((b << 11) + j)) << 11) + i];
    if (fabsf(fc - fm) > 1e-3f || fabsf(fc - fm2) > 1e-3f)
      atomicOr(flag, 1);
  }
}

// ---------- K3c: conditional VALU fallback (proven round-6 cyclic GEMM) ---
__global__ __launch_bounds__(256, 3) void k_cyc_cond(
    const double* __restrict__ xnD, const double* __restrict__ sq,
    float* __restrict__ distM, const int* __restrict__ flag) {
  if (*flag == 0) return;             // uniform early-exit
  __shared__ double rowd[DDIM][ROWS];
  const int b = blockIdx.x & 7;
  const int g = blockIdx.x >> 3;      // 0..255
  const int i0 = g << 3;
  const int t = threadIdx.x;
  const double* Xb = xnD + (size_t)b * DDIM * NN;
  #pragma unroll
  for (int q = 0; q < 4; ++q) {
    const int idx = (t << 2) + q;
    const int d = idx >> 3, r = idx & 7;
    rowd[d][r] = Xb[((size_t)d << 11) + i0 + r];
  }
  __syncthreads();
  const int c = (i0 + (t << 2)) & (NN - 1);
  double acc[ROWS][4];
  #pragma unroll
  for (int r = 0; r < ROWS; ++r)
    #pragma unroll
    for (int q = 0; q < 4; ++q) acc[r][q] = 0.0;
  const double* colp = Xb + c;
  for (int d = 0; d < DDIM; ++d) {
    const double* cp = colp + ((size_t)d << 11);
    const double2 p0 = *(const double2*)cp;
    const double2 p1 = *(const double2*)(cp + 2);
    #pragma unroll
    for (int r = 0; r < ROWS; ++r) {
      const double rv = rowd[d][r];
      acc[r][0] = fma(rv, p0.x, acc[r][0]);
      acc[r][1] = fma(rv, p0.y, acc[r][1]);
      acc[r][2] = fma(rv, p1.x, acc[r][2]);
      acc[r][3] = fma(rv, p1.y, acc[r][3]);
    }
  }
  const double* sqb = sq + (b << 11);
  const double sqc0 = sqb[c], sqc1 = sqb[c + 1], sqc2 = sqb[c + 2], sqc3 = sqb[c + 3];
  float f[ROWS][4];
  #pragma unroll
  for (int r = 0; r < ROWS; ++r) {
    const double sqi = sqb[i0 + r];
    double d2;
    d2 = (sqi + sqc0) - 2.0 * acc[r][0]; if (d2 < 0.0) d2 = 0.0; f[r][0] = (float)sqrt(d2);
    d2 = (sqi + sqc1) - 2.0 * acc[r][1]; if (d2 < 0.0) d2 = 0.0; f[r][1] = (float)sqrt(d2);
    d2 = (sqi + sqc2) - 2.0 * acc[r][2]; if (d2 < 0.0) d2 = 0.0; f[r][2] = (float)sqrt(d2);
    d2 = (sqi + sqc3) - 2.0 * acc[r][3]; if (d2 < 0.0) d2 = 0.0; f[r][3] = (float)sqrt(d2);
    *(float4*)(distM + (((size_t)((b << 11) + i0 + r)) << 11) + c) =
        make_float4(f[r][0], f[r][1], f[r][2], f[r][3]);
  }
  #pragma unroll
  for (int q = 0; q < 4; ++q) {
    float* trow = distM + (((size_t)((b << 11) + c + q)) << 11) + i0;
    *(float4*)(trow)     = make_float4(f[0][q], f[1][q], f[2][q], f[3][q]);
    *(float4*)(trow + 4) = make_float4(f[4][q], f[5][q], f[6][q], f[7][q]);
  }
}

// ---------- K4: wave-per-row radix select ----------
__global__ __launch_bounds__(256) void k_sel(const float* __restrict__ dist,
                                             float* __restrict__ kth) {
  const int row = (blockIdx.x << 2) + (threadIdx.x >> 6);
  const int l = threadIdx.x & 63;
  const float4* r4 = (const float4*)(dist + ((size_t)row << 11));
  unsigned u[32];
  #pragma unroll
  for (int jj = 0; jj < 8; ++jj) {
    const float4 fv = r4[(jj << 6) + l];
    u[jj * 4 + 0] = __float_as_uint(fv.x);
    u[jj * 4 + 1] = __float_as_uint(fv.y);
    u[jj * 4 + 2] = __float_as_uint(fv.z);
    u[jj * 4 + 3] = __float_as_uint(fv.w);
  }
  unsigned pref = 0;
  for (int bit = 30; bit >= 0; --bit) {
    const unsigned mid = pref | (1u << bit);
    int c = 0;
    #pragma unroll
    for (int k = 0; k < 32; ++k)
      c += (int)__popcll(__ballot(u[k] < mid));
    if (c <= KSEL) pref = mid;
  }
  if (l == 0) kth[row] = __uint_as_float(pref);
}

// ---------- K5: mean of 2048 floats ----------
__global__ __launch_bounds__(256) void k_mean2048(const float* __restrict__ in,
                                                  float* __restrict__ out) {
  __shared__ double lds[4];
  const int b = blockIdx.x, t = threadIdx.x;
  const float* p = in + (b << 11);
  double s = 0.0;
  #pragma unroll
  for (int q = 0; q < 8; ++q) s += (double)p[t + q * 256];
  s = blockReduceD(s, lds);
  if (t == 0) out[b] = (float)(s * (1.0 / 2048.0));
}

// ---------- K6: counts; samples by row scan, neighbors by king gather ----
__global__ __launch_bounds__(256) void k_count_geo(
    const float* __restrict__ dist, const float* __restrict__ Rf,
    float* __restrict__ samples, float* __restrict__ neigh,
    float* __restrict__ degree) {
  __shared__ int pS[4];
  const int bi = blockIdx.x;
  const int b = bi >> 11, i = bi & 2047;
  const int t = threadIdx.x, w = t >> 6, l = t & 63;
  const float R = Rf[b];
  const float* drow = dist + ((size_t)bi << 11);
  const float4* d4 = (const float4*)drow + (t << 1);
  const float4 d0 = d4[0], d1 = d4[1];
  const float f[8] = {d0.x, d0.y, d0.z, d0.w, d1.x, d1.y, d1.z, d1.w};
  int sN = 0;
  #pragma unroll
  for (int q = 0; q < 8; ++q) sN += (int)__popcll(__ballot(f[q] < R));
  if (l == 0) pS[w] = sN;
  __syncthreads();
  if (t < 64) {
    bool inb = false, ok = false;
    if (l < 8) {
      const int m = (l < 4) ? l : l + 1;
      const int di = m / 3 - 1, dj = m % 3 - 1;
      const int rj = (i >> 6) + di, cj = (i & 63) + dj;
      inb = ((unsigned)rj < 32u) && ((unsigned)cj < 64u);
      if (inb) {
        const float fv = drow[(rj << 6) + cj];
        ok = (fv != 0.0f) && (fv < R);
      }
    }
    const int nN = (int)__popcll(__ballot(ok));
    const int dc = (int)__popcll(__ballot(inb));
    if (t == 0) {
      samples[bi] = (float)(pS[0] + pS[1] + pS[2] + pS[3]);
      neigh[bi]   = (float)nN;
      if (b == 0) degree[i] = (float)dc;
    }
  }
}

// ---------- K7: mean(samples) + score + stable rank + mask ----------
__global__ __launch_bounds__(256) void k_rank_score(
    const float* __restrict__ samples, const float* __restrict__ neigh,
    const float* __restrict__ degree, float* __restrict__ score,
    float* __restrict__ mask) {
  __shared__ double lds[4];
  __shared__ float mfs;
  __shared__ float sc[NN];
  const int b = blockIdx.x >> 3, chunk = blockIdx.x & 7, t = threadIdx.x;
  const float* p = samples + (b << 11);
  double s = 0.0;
  #pragma unroll
  for (int q = 0; q < 8; ++q) s += (double)p[t + q * 256];
  s = blockReduceD(s, lds);
  if (t == 0) mfs = (float)(s * (1.0 / 2048.0));
  __syncthreads();
  const float mf = mfs;
  #pragma unroll
  for (int q = 0; q < 8; ++q) {
    const int i = t + q * 256;
    const int g = (b << 11) + i;
    const float sp = neigh[g] / degree[i];
    const float sv = p[i];
    const float tp = sv / (sv + mf);
    const float v = (2.0f - sp) - tp;
    sc[i] = v;
    if (chunk == 0) score[g] = v;
  }
  __syncthreads();
  const int i = chunk * 256 + t;
  const float si = sc[i];
  int less = 0, eqb = 0;
  for (int j = 0; j < NN; ++j) {
    const float sj = sc[j];
    less += (sj < si) ? 1 : 0;
    eqb  += ((sj == si) && (j < i)) ? 1 : 0;
  }
  mask[(b << 11) + i] = ((less + eqb) < KEEP) ? 1.0f : 0.0f;
}

// ---------- K8: out = data * mask ----------
__global__ __launch_bounds__(256) void k_apply(const float* __restrict__ data,
                                               const float* __restrict__ mask,
                                               float* __restrict__ out) {
  const int g = blockIdx.x * 256 + threadIdx.x;
  const float4 d = ((const float4*)data)[g];
  const int idx = g << 2;
  const int b = idx >> 18;
  const int w = idx & 2047;
  const float4 mk = *(const float4*)(mask + (b << 11) + w);
  float4 o;
  o.x = d.x * mk.x; o.y = d.y * mk.y; o.z = d.z * mk.z; o.w = d.w * mk.w;
  ((float4*)out)[g] = o;
}

extern "C" void kernel_launch(void* const* d_in, const int* in_sizes, int n_in,
                              void* d_out, int out_size, void* d_ws, size_t ws_size,
                              hipStream_t stream) {
  (void)in_sizes; (void)n_in; (void)out_size; (void)ws_size;
  const float* data = (const float*)d_in[0];
  float* out = (float*)d_out;
  float* score = out + 2097152;   // total_score output slot (8*2048)

  uint8_t* w = (uint8_t*)d_ws;
  double* sq      = (double*)(w);            // 131072 B
  float*  kth     = (float*)(w + 131072);    // 65536 B
  float*  Rf      = (float*)(w + 196608);    // 32 B
  float*  samples = (float*)(w + 196672);    // 65536 B
  float*  neigh   = (float*)(w + 262208);    // 65536 B
  int*    flag    = (int*)  (w + 327744);    // 4 B
  float*  degree  = (float*)(w + 327808);    // 8192 B
  float*  mask    = (float*)(w + 336000);    // 65536 B
  int*    rowmap  = (int*)  (w + 401536);    // 1024 B
  int*    colmap  = (int*)  (w + 402560);    // 1024 B

  const size_t xnDBytes = (size_t)BZ * DDIM * NN * sizeof(double); // 16777216
  double* xnD   = (double*)(w + 1048576);
  float*  distM = (float*)(w + 1048576 + xnDBytes);

  k_normD   <<<1024, 256, 0, stream>>>(data, xnD, flag);
  k_sq_probe<<<65,   256, 0, stream>>>(xnD, sq, flag, rowmap, colmap);
  k_mfma    <<<1024, 256, 0, stream>>>(xnD, sq, distM, flag, rowmap, colmap);
  k_anti_check<<<520, 256, 0, stream>>>(xnD, sq, distM, flag);
  k_cyc_cond<<<2048, 256, 0, stream>>>(xnD, sq, distM, flag);
  k_sel     <<<4096, 256, 0, stream>>>(distM, kth);
  k_mean2048<<<8,    256, 0, stream>>>(kth, Rf);
  k_count_geo<<<16384, 256, 0, stream>>>(distM, Rf, samples, neigh, degree);
  k_rank_score<<<64, 256, 0, stream>>>(samples, neigh, degree, score, mask);
  k_apply   <<<2048, 256, 0, stream>>>(data, mask, out);
}